// Round 3
// baseline (2696.850 us; speedup 1.0000x reference)
//
#include <hip/hip_runtime.h>
#include <hip/hip_bf16.h>
#include <hip/hip_cooperative_groups.h>

namespace cg = cooperative_groups;

typedef __attribute__((ext_vector_type(8))) short short8;
typedef __attribute__((ext_vector_type(4))) float f32x4;
typedef unsigned short u16;

// Problem constants
#define BB 512     // batch
#define HH 1024    // hidden
#define TT 25      // decoder steps
#define CTB 128    // ct slices (each owns 8 hidden cols -> 48 Wc rows)

__device__ __forceinline__ float sigm(float x){ return 1.f/(1.f+__expf(-x)); }
__device__ __forceinline__ float tanh_(float x){
  float e = __expf(-2.f*fabsf(x));
  float t = (1.f-e)/(1.f+e);
  return copysignf(t, x);
}
__device__ __forceinline__ u16 f2bf(float x){
  union { float f; unsigned u; } v; v.f = x;
  unsigned r = v.u + 0x7FFFu + ((v.u>>16)&1u);
  return (u16)(r>>16);
}

// Wcp layout: per ct slice (8 hidden cols), 48 rows (r = gate*8 + u, gates:
// 0=gir 1=giz 2=gin 3=ghr 4=ghz 5=ghn), pre-packed in MFMA B-frag order:
// elem idx = ct*49152 + ((kit*3 + nf)*64 + lane)*8 + e
__device__ __forceinline__ size_t wc_idx(int ct, int r, int k){
  int nf = r>>4, rl = r&15, kit = k>>5, k31 = k&31;
  int lane = rl | (((k31>>3)&3)<<4);
  return (size_t)ct*49152 + ((size_t)(kit*3+nf)*64 + (size_t)lane)*8 + (k31&7);
}

// ---- prep 1: Whh -> Wcp gate rows 3..5 (+cbias), Wout -> WoT (bf16 [96][1024])
__global__ void k_prep_cast(const float* __restrict__ Whh, const float* __restrict__ bhh,
                            const float* __restrict__ Wout,
                            u16* __restrict__ Wcp, float* __restrict__ cbias,
                            u16* __restrict__ WoT){
  int bid = blockIdx.x, tid = threadIdx.x;
  if (bid < 3072){
    int g1 = bid >> 10, j = bid & 1023;
    int ct = j >> 3, u = j & 7, r = (3+g1)*8 + u;
    const float* src = Whh + (size_t)bid*1024;
    if (tid < 128){
      int k0 = tid*8;
      size_t base = wc_idx(ct, r, k0);
      #pragma unroll
      for (int i=0;i<8;i++) Wcp[base+i] = f2bf(src[k0+i]);
    }
    if (!tid) cbias[ct*48 + r] = bhh[bid];
  } else {
    int d = bid - 3072;
    for (int k = tid; k < 1024; k += 256)
      WoT[(size_t)d*1024 + k] = f2bf(Wout[(size_t)k*96 + d]);
  }
}

// ---- prep 2: Wx[n][k] = sum_d Wih[n][d]*Wout[k][d]  (out-proj folded into gi path)
__global__ void k_prep_wx(const float* __restrict__ Wih, const float* __restrict__ Wout,
                          u16* __restrict__ Wcp){
  __shared__ float sWih[32][97];
  __shared__ float sWo[64][97];
  int tid = threadIdx.x;
  int nt = blockIdx.x % 96, kt = blockIdx.x / 96;   // n-tile 32, k-tile 64
  for (int i = tid; i < 32*96; i += 256){ int r2=i/96, d=i%96; sWih[r2][d] = Wih[(size_t)(nt*32+r2)*96 + d]; }
  for (int i = tid; i < 64*96; i += 256){ int r2=i/96, d=i%96; sWo[r2][d]  = Wout[(size_t)(kt*64+r2)*96 + d]; }
  __syncthreads();
  int ni = tid & 31, kb = tid >> 5;    // thread owns 8 consecutive k
  float acc[8];
  #pragma unroll
  for (int i=0;i<8;i++) acc[i]=0.f;
  for (int d = 0; d < 96; d++){
    float a = sWih[ni][d];
    #pragma unroll
    for (int i=0;i<8;i++) acc[i] += a * sWo[kb*8 + i][d];
  }
  int n = nt*32 + ni;
  int g = n >> 10, j = n & 1023;
  int ct = j >> 3, u = j & 7, r = g*8 + u;
  size_t base = wc_idx(ct, r, kt*64 + kb*8);
  #pragma unroll
  for (int i=0;i<8;i++) Wcp[base+i] = f2bf(acc[i]);
}

// ---- prep 3: cbias gi rows: bih[n] + sum_d bout[d]*Wih[n][d]
__global__ void k_prep_cx(const float* __restrict__ Wih, const float* __restrict__ bih,
                          const float* __restrict__ bout, float* __restrict__ cbias){
  int n = blockIdx.x*256 + threadIdx.x;
  if (n >= 3072) return;
  float acc = bih[n];
  const float* wrow = Wih + (size_t)n*96;
  for (int d = 0; d < 96; d++) acc += bout[d]*wrow[d];
  int g = n >> 10, j = n & 1023;
  cbias[(j>>3)*48 + g*8 + (j&7)] = acc;
}

// ---- step 0: h1 = gru(p, 0) in fp32 (gh = bhh exactly since h=0)
__global__ void k_step0(const float* __restrict__ dec_in, const float* __restrict__ Wih,
                        const float* __restrict__ bih, const float* __restrict__ bhh,
                        float* __restrict__ h_f32, u16* __restrict__ h_bf){
  __shared__ float sP[64][97];
  __shared__ float sW[64][97];
  int tid = threadIdx.x;
  int bt = blockIdx.x & 7;
  int jt = blockIdx.x >> 3;
  for (int i = tid; i < 64*96; i += 256){ int r=i/96, d=i%96; sP[r][d] = dec_in[(size_t)(bt*64+r)*96 + d]; }
  int tb = tid >> 4, tj = tid & 15;
  float gg[3][4][4];
  for (int g = 0; g < 3; g++){
    __syncthreads();
    for (int i = tid; i < 64*96; i += 256){ int r=i/96, d=i%96; sW[r][d] = Wih[((size_t)g*1024 + jt*64 + r)*96 + d]; }
    __syncthreads();
    float acc[4][4];
    #pragma unroll
    for (int x=0;x<4;x++)
      #pragma unroll
      for (int y=0;y<4;y++) acc[x][y]=0.f;
    for (int d = 0; d < 96; d++){
      float a[4], wv[4];
      #pragma unroll
      for (int x=0;x<4;x++) a[x]  = sP[tb + x*16][d];
      #pragma unroll
      for (int y=0;y<4;y++) wv[y] = sW[tj + y*16][d];
      #pragma unroll
      for (int x=0;x<4;x++)
        #pragma unroll
        for (int y=0;y<4;y++) acc[x][y] += a[x]*wv[y];
    }
    #pragma unroll
    for (int x=0;x<4;x++)
      #pragma unroll
      for (int y=0;y<4;y++) gg[g][x][y] = acc[x][y];
  }
  #pragma unroll
  for (int x=0;x<4;x++)
    #pragma unroll
    for (int y=0;y<4;y++){
      int b = bt*64 + tb + x*16;
      int j = jt*64 + tj + y*16;
      float gir = gg[0][x][y] + bih[j];
      float giz = gg[1][x][y] + bih[1024+j];
      float gin = gg[2][x][y] + bih[2048+j];
      float r = sigm(gir + bhh[j]);
      float z = sigm(giz + bhh[1024+j]);
      float nn = tanh_(gin + r*bhh[2048+j]);
      float h = (1.f - z)*nn;
      h_f32[(size_t)b*1024 + j] = h;
      h_bf [(size_t)b*1024 + j] = f2bf(h);
    }
}

// ---- persistent kernel: all 25 steps; Wc slice lives in LDS for the whole run.
// 256 blocks x 512 threads, 1 block/CU (LDS 96 KB), grid-sync between steps.
__global__ __launch_bounds__(512)
void k_persist(const u16* __restrict__ hb0, float* __restrict__ hf0,
               u16* __restrict__ hb1, float* __restrict__ hf1,
               const u16* __restrict__ Wcp, const float* __restrict__ cbias,
               const u16* __restrict__ WoT, const float* __restrict__ bout,
               float* __restrict__ pred){
  __shared__ short8 sB[6144];       // 96 KB: Wc slice in B-frag order
  cg::grid_group grid = cg::this_grid();

  int b = blockIdx.x, tid = threadIdx.x;
  int lane = tid & 63, w = tid >> 6;          // 8 waves
  int l16 = lane & 15, lk = lane >> 4;
  int r8 = b & 7;
  int bt = r8 >> 2;                           // batch half: XCDs 0-3 -> 0, 4-7 -> 1
  int ib = (b >> 3)*4 + (r8 & 3);             // slice index within half [0,128)
  int ct = ib;

  // stage Wc slice once
  {
    const short8* Wblk = (const short8*)Wcp + (size_t)ct*6144;
    for (int i = tid; i < 6144; i += 512) sB[i] = Wblk[i];
  }
  __syncthreads();

  const u16* hbv[2] = {hb0, hb1};
  float*     hfv[2] = {hf0, hf1};

  float c0 = cbias[ct*48 +  0 + l16];
  float c1 = cbias[ct*48 + 16 + l16];
  float c2 = cbias[ct*48 + 32 + l16];
  bool hiB = (l16 & 8) != 0;
  int colg = ct*8 + (l16 & 7);

  // pred tile assignment: per half, 96 tiles (16 bm x 6 bn), wave 7 of blocks ib<96
  int bm = ib / 6, bn = ib % 6;
  bool doPred = (w == 7) && (ib < 96);

  for (int t = 1; t <= 25; t++){
    const u16*  hin_bf  = hbv[(t-1)&1];
    const float* hin_f32 = hfv[(t-1)&1];

    // ---- fused out-projection: pred[t-1] = h_t @ Wout + bout
    if (doPred){
      const short8* Aq = (const short8*)hin_bf + (size_t)(bt*256 + bm*16 + l16)*128 + lk;
      const short8* Bq = (const short8*)WoT   + (size_t)(bn*16 + l16)*128 + lk;
      f32x4 accp = {0.f,0.f,0.f,0.f};
      #pragma unroll 4
      for (int kit = 0; kit < 32; kit++)
        accp = __builtin_amdgcn_mfma_f32_16x16x32_bf16(Aq[kit*4], Bq[kit*4], accp, 0,0,0);
      int c = bn*16 + l16;
      float bb = bout[c];
      #pragma unroll
      for (int j=0;j<4;j++){
        int row = bt*256 + bm*16 + lk*4 + j;
        pred[(size_t)row*2400 + (size_t)(t-1)*96 + c] = accp[j] + bb;
      }
    }

    if (t < 25){
      float* hout_f32 = hfv[t&1];
      u16*   hout_bf  = (u16*)hbv[t&1];

      // ---- recurrence: C = h_t[half] @ WcSlice^T
      int rowA = bt*256 + w*32;
      const short8* Ap = (const short8*)hin_bf + (size_t)(rowA + l16)*128 + lk;
      short8 a0 = Ap[0];
      short8 a1 = Ap[2048];                    // +16 batch rows
      f32x4 acc[2][3];
      #pragma unroll
      for (int m=0;m<2;m++)
        #pragma unroll
        for (int nf=0;nf<3;nf++) acc[m][nf] = f32x4{0.f,0.f,0.f,0.f};
      #pragma unroll 4
      for (int kit = 0; kit < 32; kit++){
        short8 n0, n1;
        if (kit < 31){ n0 = Ap[4]; n1 = Ap[2052]; }
        const short8* Bs = &sB[kit*192 + lane];
        short8 b0 = Bs[0], b1 = Bs[64], b2 = Bs[128];
        acc[0][0] = __builtin_amdgcn_mfma_f32_16x16x32_bf16(a0, b0, acc[0][0], 0,0,0);
        acc[1][0] = __builtin_amdgcn_mfma_f32_16x16x32_bf16(a1, b0, acc[1][0], 0,0,0);
        acc[0][1] = __builtin_amdgcn_mfma_f32_16x16x32_bf16(a0, b1, acc[0][1], 0,0,0);
        acc[1][1] = __builtin_amdgcn_mfma_f32_16x16x32_bf16(a1, b1, acc[1][1], 0,0,0);
        acc[0][2] = __builtin_amdgcn_mfma_f32_16x16x32_bf16(a0, b2, acc[0][2], 0,0,0);
        acc[1][2] = __builtin_amdgcn_mfma_f32_16x16x32_bf16(a1, b2, acc[1][2], 0,0,0);
        a0 = n0; a1 = n1; Ap += 4;
      }

      // gate math: lane pair (l, l^8): lo has gir,gin,ghz; hi has giz,ghr,ghn
      #pragma unroll
      for (int mf=0; mf<2; mf++){
        #pragma unroll
        for (int j=0;j<4;j++){
          int batch = rowA + mf*16 + lk*4 + j;
          float g0 = acc[mf][0][j] + c0;   // lo: gir   hi: giz
          float g1 = acc[mf][1][j] + c1;   // lo: gin   hi: ghr
          float g2 = acc[mf][2][j] + c2;   // lo: ghz   hi: ghn
          float v1 = hiB ? g1 : g2;                 // hi sends ghr, lo sends ghz
          float w1 = __shfl_xor(v1, 8, 64);
          float rz = sigm(g0 + w1);                 // lo: r, hi: z
          float w2 = __shfl_xor(rz, 8, 64);         // lo gets z, hi gets r
          float v3 = hiB ? (w2 * g2) : 0.f;         // hi: r*ghn
          float w3 = __shfl_xor(v3, 8, 64);         // lo gets r*ghn
          if (!hiB){
            float nn = tanh_(g1 + w3);
            float z  = w2;
            float hold = hin_f32[(size_t)batch*1024 + colg];
            float hnew = (1.f - z)*nn + z*hold;
            hout_f32[(size_t)batch*1024 + colg] = hnew;
            hout_bf [(size_t)batch*1024 + colg] = f2bf(hnew);
          }
        }
      }
      __threadfence();
      grid.sync();
    }
  }
}

extern "C" void kernel_launch(void* const* d_in, const int* in_sizes, int n_in,
                              void* d_out, int out_size, void* d_ws, size_t ws_size,
                              hipStream_t stream){
  // inputs: 0 enc_in, 1 dec_in, 2..5 enc_* (DEAD CODE), 6 dec_Wih, 7 dec_Whh,
  //         8 dec_bih, 9 dec_bhh, 10 W_out, 11 b_out
  const float* dec_in = (const float*)d_in[1];
  const float* Wih  = (const float*)d_in[6];
  const float* Whh  = (const float*)d_in[7];
  const float* bih  = (const float*)d_in[8];
  const float* bhh  = (const float*)d_in[9];
  const float* Wout = (const float*)d_in[10];
  const float* bout = (const float*)d_in[11];
  float* pred = (float*)d_out;   // [512][25][96] fp32

  char* ws = (char*)d_ws;
  size_t off = 0;
  u16* Wcp = (u16*)(ws + off);   off += (size_t)CTB*48*1024*2;     // 12.58 MB
  u16* WoT = (u16*)(ws + off);   off += (size_t)96*1024*2;         // 196 KB
  float* cbias = (float*)(ws + off); off += (size_t)6144*4;
  off = (off + 255) & ~(size_t)255;
  float* hfA = (float*)(ws + off); off += (size_t)BB*HH*4;
  float* hfB = (float*)(ws + off); off += (size_t)BB*HH*4;
  u16* hbA = (u16*)(ws + off);     off += (size_t)BB*HH*2;
  u16* hbB = (u16*)(ws + off);     off += (size_t)BB*HH*2;

  k_prep_cast<<<3168, 256, 0, stream>>>(Whh, bhh, Wout, Wcp, cbias, WoT);
  k_prep_wx  <<<1536, 256, 0, stream>>>(Wih, Wout, Wcp);
  k_prep_cx  <<<12,   256, 0, stream>>>(Wih, bih, bout, cbias);
  k_step0    <<<128,  256, 0, stream>>>(dec_in, Wih, bih, bhh, hfA, hbA);

  const u16* hbA_c = hbA;
  void* kargs[] = {(void*)&hbA_c, (void*)&hfA, (void*)&hbB, (void*)&hfB,
                   (void*)&Wcp, (void*)&cbias, (void*)&WoT, (void*)&bout,
                   (void*)&pred};
  hipLaunchCooperativeKernel((const void*)k_persist, dim3(256), dim3(512),
                             kargs, 0, stream);
}

// Round 4
// 675.289 us; speedup vs baseline: 3.9936x; 3.9936x over previous
//
#include <hip/hip_runtime.h>
#include <hip/hip_bf16.h>

typedef __attribute__((ext_vector_type(8))) short short8;
typedef __attribute__((ext_vector_type(4))) float f32x4;
typedef unsigned short u16;

// Problem constants
#define BB 512     // batch
#define HH 1024    // hidden
#define TT 25      // decoder steps
#define CTB 128    // ct slices (each owns 8 hidden cols -> 48 Wc rows)

__device__ __forceinline__ float sigm(float x){ return 1.f/(1.f+__expf(-x)); }
__device__ __forceinline__ float tanh_(float x){
  float e = __expf(-2.f*fabsf(x));
  float t = (1.f-e)/(1.f+e);
  return copysignf(t, x);
}
__device__ __forceinline__ u16 f2bf(float x){
  union { float f; unsigned u; } v; v.f = x;
  unsigned r = v.u + 0x7FFFu + ((v.u>>16)&1u);
  return (u16)(r>>16);
}

#if __has_builtin(__builtin_amdgcn_global_load_lds)
#define GLOAD_LDS16(g, l) __builtin_amdgcn_global_load_lds( \
    (const __attribute__((address_space(1))) void*)(g), \
    (__attribute__((address_space(3))) void*)(l), 16, 0, 0)
#define HAVE_GLL 1
#else
#define HAVE_GLL 0
#endif

// Wcp layout: per ct slice (8 hidden cols), 48 rows (r = gate*8 + u, gates:
// 0=gir 1=giz 2=gin 3=ghr 4=ghz 5=ghn), pre-packed in MFMA B-frag order:
// elem idx = ct*49152 + ((kit*3 + nf)*64 + lane)*8 + e
__device__ __forceinline__ size_t wc_idx(int ct, int r, int k){
  int nf = r>>4, rl = r&15, kit = k>>5, k31 = k&31;
  int lane = rl | (((k31>>3)&3)<<4);
  return (size_t)ct*49152 + ((size_t)(kit*3+nf)*64 + (size_t)lane)*8 + (k31&7);
}

// ---- prep 1: Whh -> Wcp gate rows 3..5 (+cbias), Wout -> WoT (bf16 [96][1024])
__global__ void k_prep_cast(const float* __restrict__ Whh, const float* __restrict__ bhh,
                            const float* __restrict__ Wout,
                            u16* __restrict__ Wcp, float* __restrict__ cbias,
                            u16* __restrict__ WoT){
  int bid = blockIdx.x, tid = threadIdx.x;
  if (bid < 3072){
    int g1 = bid >> 10, j = bid & 1023;
    int ct = j >> 3, u = j & 7, r = (3+g1)*8 + u;
    const float* src = Whh + (size_t)bid*1024;
    if (tid < 128){
      int k0 = tid*8;
      size_t base = wc_idx(ct, r, k0);
      #pragma unroll
      for (int i=0;i<8;i++) Wcp[base+i] = f2bf(src[k0+i]);
    }
    if (!tid) cbias[ct*48 + r] = bhh[bid];
  } else {
    int d = bid - 3072;
    for (int k = tid; k < 1024; k += 256)
      WoT[(size_t)d*1024 + k] = f2bf(Wout[(size_t)k*96 + d]);
  }
}

// ---- prep 2: Wx[n][k] = sum_d Wih[n][d]*Wout[k][d]  (out-proj folded into gi path)
__global__ void k_prep_wx(const float* __restrict__ Wih, const float* __restrict__ Wout,
                          u16* __restrict__ Wcp){
  __shared__ float sWih[32][97];
  __shared__ float sWo[64][97];
  int tid = threadIdx.x;
  int nt = blockIdx.x % 96, kt = blockIdx.x / 96;   // n-tile 32, k-tile 64
  for (int i = tid; i < 32*96; i += 256){ int r2=i/96, d=i%96; sWih[r2][d] = Wih[(size_t)(nt*32+r2)*96 + d]; }
  for (int i = tid; i < 64*96; i += 256){ int r2=i/96, d=i%96; sWo[r2][d]  = Wout[(size_t)(kt*64+r2)*96 + d]; }
  __syncthreads();
  int ni = tid & 31, kb = tid >> 5;    // thread owns 8 consecutive k
  float acc[8];
  #pragma unroll
  for (int i=0;i<8;i++) acc[i]=0.f;
  for (int d = 0; d < 96; d++){
    float a = sWih[ni][d];
    #pragma unroll
    for (int i=0;i<8;i++) acc[i] += a * sWo[kb*8 + i][d];
  }
  int n = nt*32 + ni;
  int g = n >> 10, j = n & 1023;
  int ct = j >> 3, u = j & 7, r = g*8 + u;
  size_t base = wc_idx(ct, r, kt*64 + kb*8);
  #pragma unroll
  for (int i=0;i<8;i++) Wcp[base+i] = f2bf(acc[i]);
}

// ---- prep 3: cbias gi rows: bih[n] + sum_d bout[d]*Wih[n][d]
__global__ void k_prep_cx(const float* __restrict__ Wih, const float* __restrict__ bih,
                          const float* __restrict__ bout, float* __restrict__ cbias){
  int n = blockIdx.x*256 + threadIdx.x;
  if (n >= 3072) return;
  float acc = bih[n];
  const float* wrow = Wih + (size_t)n*96;
  for (int d = 0; d < 96; d++) acc += bout[d]*wrow[d];
  int g = n >> 10, j = n & 1023;
  cbias[(j>>3)*48 + g*8 + (j&7)] = acc;
}

// ---- step 0: h1 = gru(p, 0) in fp32 (gh = bhh exactly since h=0)
// h_f32 written COL-MAJOR [1024][512]; h_bf row-major [512][1024]
__global__ void k_step0(const float* __restrict__ dec_in, const float* __restrict__ Wih,
                        const float* __restrict__ bih, const float* __restrict__ bhh,
                        float* __restrict__ h_f32, u16* __restrict__ h_bf){
  __shared__ float sP[64][97];
  __shared__ float sW[64][97];
  int tid = threadIdx.x;
  int bt = blockIdx.x & 7;
  int jt = blockIdx.x >> 3;
  for (int i = tid; i < 64*96; i += 256){ int r=i/96, d=i%96; sP[r][d] = dec_in[(size_t)(bt*64+r)*96 + d]; }
  int tb = tid >> 4, tj = tid & 15;
  float gg[3][4][4];
  for (int g = 0; g < 3; g++){
    __syncthreads();
    for (int i = tid; i < 64*96; i += 256){ int r=i/96, d=i%96; sW[r][d] = Wih[((size_t)g*1024 + jt*64 + r)*96 + d]; }
    __syncthreads();
    float acc[4][4];
    #pragma unroll
    for (int x=0;x<4;x++)
      #pragma unroll
      for (int y=0;y<4;y++) acc[x][y]=0.f;
    for (int d = 0; d < 96; d++){
      float a[4], wv[4];
      #pragma unroll
      for (int x=0;x<4;x++) a[x]  = sP[tb + x*16][d];
      #pragma unroll
      for (int y=0;y<4;y++) wv[y] = sW[tj + y*16][d];
      #pragma unroll
      for (int x=0;x<4;x++)
        #pragma unroll
        for (int y=0;y<4;y++) acc[x][y] += a[x]*wv[y];
    }
    #pragma unroll
    for (int x=0;x<4;x++)
      #pragma unroll
      for (int y=0;y<4;y++) gg[g][x][y] = acc[x][y];
  }
  #pragma unroll
  for (int x=0;x<4;x++)
    #pragma unroll
    for (int y=0;y<4;y++){
      int b = bt*64 + tb + x*16;
      int j = jt*64 + tj + y*16;
      float gir = gg[0][x][y] + bih[j];
      float giz = gg[1][x][y] + bih[1024+j];
      float gin = gg[2][x][y] + bih[2048+j];
      float r = sigm(gir + bhh[j]);
      float z = sigm(giz + bhh[1024+j]);
      float nn = tanh_(gin + r*bhh[2048+j]);
      float h = (1.f - z)*nn;
      h_f32[(size_t)j*512 + b] = h;
      h_bf [(size_t)b*1024 + j] = f2bf(h);
    }
}

// ---- main step: async LDS staging + deep A prefetch; 256 blocks x 512 thr.
// blocks tile (batch half 256) x (ct slice: 8 hidden cols = 48 gate rows).
// Fused out-projection pred[t-1] = h_t @ Wout + bout on wave 7 of ib<96 blocks.
__global__ __launch_bounds__(512)
void k_step3(const u16* __restrict__ hin_bf, const float* __restrict__ hin_f32,
             const u16* __restrict__ Wcp, const float* __restrict__ cbias,
             const u16* __restrict__ WoT, const float* __restrict__ bout,
             float* __restrict__ hout_f32, u16* __restrict__ hout_bf,
             float* __restrict__ pred, int tm1, int do_recur){
  __shared__ short8 sB[6144];       // 96 KB: Wc slice in B-frag order
  int b = blockIdx.x, tid = threadIdx.x;
  int lane = tid & 63, w = tid >> 6;          // 8 waves
  int l16 = lane & 15, lk = lane >> 4;
  // XCD-stable mapping: b&7 -> XCD; XCDs 0-3 own batch half 0, 4-7 half 1.
  int r8 = b & 7;
  int bt = r8 >> 2;
  int ct = (b >> 3)*4 + (r8 & 3);             // ct in [0,128)

  // ---- phase 0: issue async Wc staging (no VGPR round-trip)
  if (do_recur){
    const short8* Wblk = (const short8*)Wcp + (size_t)ct*6144;
#if HAVE_GLL
    #pragma unroll
    for (int it = 0; it < 12; it++){
      int i = it*512 + tid;
      GLOAD_LDS16(Wblk + i, &sB[i]);
    }
#else
    for (int i = tid; i < 6144; i += 512) sB[i] = Wblk[i];
#endif
  }

  // ---- phase 1: A-prefetch ring (depth 4) + hold prefetch, overlapping DMA
  int rowA = bt*256 + w*32;
  const short8* Ap = (const short8*)hin_bf + (size_t)(rowA + l16)*128 + lk;
  bool hiB = (l16 & 8) != 0;
  int colg = ct*8 + (l16 & 7);
  short8 ra0[4], ra1[4];
  float hold[2][4];
  if (do_recur){
    #pragma unroll
    for (int d = 0; d < 4; d++){ ra0[d] = Ap[d*4]; ra1[d] = Ap[d*4 + 2048]; }
    if (!hiB){
      #pragma unroll
      for (int mf=0; mf<2; mf++)
        #pragma unroll
        for (int j=0;j<4;j++)
          hold[mf][j] = hin_f32[(size_t)colg*512 + rowA + mf*16 + lk*4 + j];
    }
  }

  // ---- phase 2: fused out-projection (wave 7, ib<96 per half), overlaps DMA
  if (w == 7 && ct < 96){
    int bm = ct / 6, bn = ct % 6;
    const short8* Aq = (const short8*)hin_bf + (size_t)(bt*256 + bm*16 + l16)*128 + lk;
    const short8* Bq = (const short8*)WoT   + (size_t)(bn*16 + l16)*128 + lk;
    f32x4 accp = {0.f,0.f,0.f,0.f};
    #pragma unroll 4
    for (int kit = 0; kit < 32; kit++)
      accp = __builtin_amdgcn_mfma_f32_16x16x32_bf16(Aq[kit*4], Bq[kit*4], accp, 0,0,0);
    int c = bn*16 + l16;
    float bb = bout[c];
    #pragma unroll
    for (int j=0;j<4;j++){
      int row = bt*256 + bm*16 + lk*4 + j;
      pred[(size_t)row*2400 + (size_t)tm1*96 + c] = accp[j] + bb;
    }
  }
  if (!do_recur) return;

  __syncthreads();   // staging (and in-flight prefetches) complete

  // ---- phase 3: recurrence C = h_t[half] @ WcSlice^T with prefetch ring
  f32x4 acc[2][3];
  #pragma unroll
  for (int m=0;m<2;m++)
    #pragma unroll
    for (int nf=0;nf<3;nf++) acc[m][nf] = f32x4{0.f,0.f,0.f,0.f};
  #pragma unroll
  for (int kit = 0; kit < 32; kit++){
    const int slot = kit & 3;
    short8 a0 = ra0[slot], a1 = ra1[slot];
    if (kit < 28){ ra0[slot] = Ap[(kit+4)*4]; ra1[slot] = Ap[(kit+4)*4 + 2048]; }
    const short8* Bs = &sB[kit*192 + lane];
    short8 b0 = Bs[0], b1 = Bs[64], b2 = Bs[128];
    acc[0][0] = __builtin_amdgcn_mfma_f32_16x16x32_bf16(a0, b0, acc[0][0], 0,0,0);
    acc[1][0] = __builtin_amdgcn_mfma_f32_16x16x32_bf16(a1, b0, acc[1][0], 0,0,0);
    acc[0][1] = __builtin_amdgcn_mfma_f32_16x16x32_bf16(a0, b1, acc[0][1], 0,0,0);
    acc[1][1] = __builtin_amdgcn_mfma_f32_16x16x32_bf16(a1, b1, acc[1][1], 0,0,0);
    acc[0][2] = __builtin_amdgcn_mfma_f32_16x16x32_bf16(a0, b2, acc[0][2], 0,0,0);
    acc[1][2] = __builtin_amdgcn_mfma_f32_16x16x32_bf16(a1, b2, acc[1][2], 0,0,0);
  }

  // ---- phase 4: gate math via lane pair (l, l^8); lo: gir,gin,ghz  hi: giz,ghr,ghn
  float c0 = cbias[ct*48 +  0 + l16];
  float c1 = cbias[ct*48 + 16 + l16];
  float c2 = cbias[ct*48 + 32 + l16];
  #pragma unroll
  for (int mf=0; mf<2; mf++){
    #pragma unroll
    for (int j=0;j<4;j++){
      int batch = rowA + mf*16 + lk*4 + j;
      float g0 = acc[mf][0][j] + c0;   // lo: gir   hi: giz
      float g1 = acc[mf][1][j] + c1;   // lo: gin   hi: ghr
      float g2 = acc[mf][2][j] + c2;   // lo: ghz   hi: ghn
      float v1 = hiB ? g1 : g2;                 // hi sends ghr, lo sends ghz
      float w1 = __shfl_xor(v1, 8, 64);
      float rz = sigm(g0 + w1);                 // lo: r, hi: z
      float w2 = __shfl_xor(rz, 8, 64);         // lo gets z, hi gets r
      float v3 = hiB ? (w2 * g2) : 0.f;         // hi: r*ghn
      float w3 = __shfl_xor(v3, 8, 64);         // lo gets r*ghn
      if (!hiB){
        float nn = tanh_(g1 + w3);
        float z  = w2;
        float hnew = (1.f - z)*nn + z*hold[mf][j];
        hout_f32[(size_t)colg*512 + batch] = hnew;
        hout_bf [(size_t)batch*1024 + colg] = f2bf(hnew);
      }
    }
  }
}

extern "C" void kernel_launch(void* const* d_in, const int* in_sizes, int n_in,
                              void* d_out, int out_size, void* d_ws, size_t ws_size,
                              hipStream_t stream){
  // inputs: 0 enc_in, 1 dec_in, 2..5 enc_* (DEAD CODE), 6 dec_Wih, 7 dec_Whh,
  //         8 dec_bih, 9 dec_bhh, 10 W_out, 11 b_out
  const float* dec_in = (const float*)d_in[1];
  const float* Wih  = (const float*)d_in[6];
  const float* Whh  = (const float*)d_in[7];
  const float* bih  = (const float*)d_in[8];
  const float* bhh  = (const float*)d_in[9];
  const float* Wout = (const float*)d_in[10];
  const float* bout = (const float*)d_in[11];
  float* pred = (float*)d_out;   // [512][25][96] fp32

  char* ws = (char*)d_ws;
  size_t off = 0;
  u16* Wcp = (u16*)(ws + off);   off += (size_t)CTB*48*1024*2;     // 12.58 MB
  u16* WoT = (u16*)(ws + off);   off += (size_t)96*1024*2;         // 196 KB
  float* cbias = (float*)(ws + off); off += (size_t)6144*4;
  off = (off + 255) & ~(size_t)255;
  float* hfA = (float*)(ws + off); off += (size_t)BB*HH*4;   // col-major [1024][512]
  float* hfB = (float*)(ws + off); off += (size_t)BB*HH*4;
  u16* hbA = (u16*)(ws + off);     off += (size_t)BB*HH*2;   // row-major [512][1024]
  u16* hbB = (u16*)(ws + off);     off += (size_t)BB*HH*2;

  k_prep_cast<<<3168, 256, 0, stream>>>(Whh, bhh, Wout, Wcp, cbias, WoT);
  k_prep_wx  <<<1536, 256, 0, stream>>>(Wih, Wout, Wcp);
  k_prep_cx  <<<12,   256, 0, stream>>>(Wih, bih, bout, cbias);
  k_step0    <<<128,  256, 0, stream>>>(dec_in, Wih, bih, bhh, hfA, hbA);

  float* hf[2] = {hfA, hfB};
  u16*   hb[2] = {hbA, hbB};
  // steps t=1..24: compute h_{t+1} AND pred[t-1] from h_t
  for (int t = 1; t <= 24; t++){
    int ci = (t-1)&1, ni = t&1;
    k_step3<<<256, 512, 0, stream>>>(hb[ci], hf[ci], Wcp, cbias, WoT, bout,
                                     hf[ni], hb[ni], pred, t-1, 1);
  }
  // final: pred[24] from h_25, no recurrence
  k_step3<<<256, 512, 0, stream>>>(hb[0], hf[0], Wcp, cbias, WoT, bout,
                                   hf[1], hb[1], pred, 24, 0);
}